// Round 10
// baseline (173.920 us; speedup 1.0000x reference)
//
#include <hip/hip_runtime.h>
#include <hip/hip_cooperative_groups.h>

namespace cg = cooperative_groups;

// BertWordEmbedder: B=64, T=512, H=768, W=256, D=256
// ONE cooperative kernel, 512 blocks x 256 thr (2/CU resident), 3 phases:
//   P0: blocks 0..191 transpose proj_w -> wt bf16 [256][768];
//       blocks 192..255 bounds[b][w] = lower_bound(wid[b,:], w)
//   P1: pool_pair (R8-proven): one wave per word pair, contiguous token
//       stream, 2-token unroll, boundary-routed accumulators -> we bf16
//   P2: gemm_lds (R6-proven): out = we @ wt^T + bias, LDS-staged MFMA,
//       XCD-chunked tile swizzle. we is L2/L3-hot (just written).
// grid.sync() between phases (device-scope visibility).
// ws: [0) wt 393216 | [393216) bounds 65792 | [524288) we 25165824

#define NB 64
#define NT 512
#define NH 768
#define NW 256
#define ND 256

typedef __attribute__((ext_vector_type(8))) short short8;
typedef __attribute__((ext_vector_type(4))) float f32x4;
typedef __attribute__((ext_vector_type(4))) float float4v;
typedef __attribute__((ext_vector_type(4))) unsigned int uint4v;
typedef __attribute__((ext_vector_type(4))) unsigned short ushort4v;

union Smem {
    struct { unsigned short A[128][72]; unsigned short B[64][72]; } g;  // 27648 B
    float tile[32][33];                                                 // 4224 B
    int s[NT];                                                          // 2048 B
};

__device__ __forceinline__ unsigned short f2bf(float f) {
    union { float f; unsigned u; } v; v.f = f;
    unsigned r = v.u + 0x7fffu + ((v.u >> 16) & 1u);  // RNE
    return (unsigned short)(r >> 16);
}

__global__ __launch_bounds__(256, 2)
void mega(const float* __restrict__ hs, const int* __restrict__ wid,
          const float* __restrict__ pw, const float* __restrict__ pb,
          unsigned short* __restrict__ wt, int* __restrict__ bounds,
          unsigned short* __restrict__ we, float* __restrict__ out) {
    cg::grid_group grid = cg::this_grid();
    __shared__ Smem sm;

    const int tid = threadIdx.x, bid = blockIdx.x;
    const int wave = tid >> 6, lane = tid & 63;

    // ---------------- Phase 0: prep ----------------
    if (bid < 192) {                              // wt transpose, 32x32 tile
        int tx = tid & 31, ty = tid >> 5;
        int k0 = (bid % 24) * 32, n0 = (bid / 24) * 32;
        #pragma unroll
        for (int i = 0; i < 4; ++i)
            sm.tile[(ty + 8 * i) * 33 / 33][0] = 0;  // no-op guard removed below
        #pragma unroll
        for (int i = 0; i < 4; ++i)
            *((float*)sm.tile + (ty + 8 * i) * 33 + tx) = pw[(size_t)(k0 + ty + 8 * i) * ND + n0 + tx];
        __syncthreads();
        #pragma unroll
        for (int i = 0; i < 4; ++i)
            wt[(size_t)(n0 + ty + 8 * i) * NH + k0 + tx] = f2bf(*((float*)sm.tile + tx * 33 + ty + 8 * i));
    } else if (bid < 256) {                       // bounds for batch b
        int b = bid - 192;
        sm.s[tid]       = wid[b * NT + tid];
        sm.s[tid + 256] = wid[b * NT + tid + 256];
        __syncthreads();
        for (int w2 = tid; w2 <= NW; w2 += 256) {
            int lo = 0, hi = NT;
            while (lo < hi) { int m = (lo + hi) >> 1; if (sm.s[m] < w2) lo = m + 1; else hi = m; }
            bounds[b * (NW + 1) + w2] = lo;
        }
    }
    grid.sync();

    // ---------------- Phase 1: pool (word pairs, grid-stride) ----------------
    for (int task = bid * 4 + wave; task < NB * NW / 2; task += 512 * 4) {
        const int b = task >> 7, j = task & 127;
        const int* bp = bounds + b * (NW + 1) + 2 * j;
        int s = __builtin_amdgcn_readfirstlane(bp[0]);
        int m = __builtin_amdgcn_readfirstlane(bp[1]);
        int e = __builtin_amdgcn_readfirstlane(bp[2]);

        const float* base = hs + (size_t)b * NT * NH + lane * 4;
        float4v a0c0 = {0,0,0,0}, a0c1 = {0,0,0,0}, a0c2 = {0,0,0,0};
        float4v a1c0 = {0,0,0,0}, a1c1 = {0,0,0,0}, a1c2 = {0,0,0,0};

#define ROUTE(t, v0, v1, v2) {                                                \
        if ((t) < m) {                                                        \
            _Pragma("unroll") for (int q = 0; q < 4; ++q) {                   \
                a0c0[q] += (v0)[q]; a0c1[q] += (v1)[q]; a0c2[q] += (v2)[q]; } \
        } else {                                                              \
            _Pragma("unroll") for (int q = 0; q < 4; ++q) {                   \
                a1c0[q] += (v0)[q]; a1c1[q] += (v1)[q]; a1c2[q] += (v2)[q]; } \
        }                                                                     \
    }
        int t = s;
        for (; t + 2 <= e; t += 2) {
            float4v v[2][3];
            #pragma unroll
            for (int u = 0; u < 2; ++u) {
                const float* p = base + (size_t)(t + u) * NH;
                v[u][0] = *(const float4v*)(p);
                v[u][1] = *(const float4v*)(p + 256);
                v[u][2] = *(const float4v*)(p + 512);
            }
            #pragma unroll
            for (int u = 0; u < 2; ++u) ROUTE(t + u, v[u][0], v[u][1], v[u][2]);
        }
        if (t < e) {
            const float* p = base + (size_t)t * NH;
            float4v v0 = *(const float4v*)(p);
            float4v v1 = *(const float4v*)(p + 256);
            float4v v2 = *(const float4v*)(p + 512);
            ROUTE(t, v0, v1, v2);
        }
#undef ROUTE
        int c0 = m - s; if (c0 < 1) c0 = 1;
        int c1 = e - m; if (c1 < 1) c1 = 1;
        const float s0 = 1.0f / (float)c0, s1 = 1.0f / (float)c1;
        unsigned short* d0 = we + (size_t)(2 * task) * NH + lane * 4;
        unsigned short* d1 = d0 + NH;
        ushort4v u;
        #pragma unroll
        for (int q = 0; q < 4; ++q) u[q] = f2bf(a0c0[q] * s0);
        *(ushort4v*)(d0) = u;
        #pragma unroll
        for (int q = 0; q < 4; ++q) u[q] = f2bf(a0c1[q] * s0);
        *(ushort4v*)(d0 + 256) = u;
        #pragma unroll
        for (int q = 0; q < 4; ++q) u[q] = f2bf(a0c2[q] * s0);
        *(ushort4v*)(d0 + 512) = u;
        #pragma unroll
        for (int q = 0; q < 4; ++q) u[q] = f2bf(a1c0[q] * s1);
        *(ushort4v*)(d1) = u;
        #pragma unroll
        for (int q = 0; q < 4; ++q) u[q] = f2bf(a1c1[q] * s1);
        *(ushort4v*)(d1 + 256) = u;
        #pragma unroll
        for (int q = 0; q < 4; ++q) u[q] = f2bf(a1c2[q] * s1);
        *(ushort4v*)(d1 + 512) = u;
    }
    grid.sync();

    // ---------------- Phase 2: gemm (R6/R9-proven) ----------------
    {
        auto& Asm = sm.g.A;
        auto& Bsm = sm.g.B;
        const int swz = (bid & 7) * 64 + (bid >> 3);    // bijective (512 % 8 == 0)
        const size_t r0 = (size_t)(swz >> 2) * 128;
        const int c0 = (swz & 3) * 64;
        const int cl = lane & 15, kg = lane >> 4;
        const int wm0 = (wave >> 1) * 64, wn0 = (wave & 1) * 32;

        const int arow = tid >> 1, ah = tid & 1;
        const int brow = tid >> 2, bq = tid & 3;
        const unsigned short* agp = we + (r0 + arow) * NH;
        const unsigned short* bgp = wt + (size_t)(c0 + brow) * NH;

        uint4v sA0[4], sB0[2], sA1[4], sB1[2];

        auto gload = [&](uint4v* sA, uint4v* sB, int k0e) {
            #pragma unroll
            for (int i = 0; i < 4; ++i)
                sA[i] = *(const uint4v*)(agp + k0e + (ah + 2 * i) * 8);
            #pragma unroll
            for (int i = 0; i < 2; ++i)
                sB[i] = *(const uint4v*)(bgp + k0e + (bq + 4 * i) * 8);
        };
        auto swrite = [&](uint4v* sA, uint4v* sB) {
            #pragma unroll
            for (int i = 0; i < 4; ++i)
                *(uint4v*)&Asm[arow][(ah + 2 * i) * 8] = sA[i];
            #pragma unroll
            for (int i = 0; i < 2; ++i)
                *(uint4v*)&Bsm[brow][(bq + 4 * i) * 8] = sB[i];
        };

        f32x4 acc[4][2];
        #pragma unroll
        for (int mt = 0; mt < 4; ++mt)
            #pragma unroll
            for (int nt = 0; nt < 2; ++nt)
                #pragma unroll
                for (int r = 0; r < 4; ++r) acc[mt][nt][r] = 0.f;

        auto compute = [&]() {
            short8 af[4][2], bf[2][2];
            #pragma unroll
            for (int mt = 0; mt < 4; ++mt)
                #pragma unroll
                for (int km = 0; km < 2; ++km)
                    af[mt][km] = *(const short8*)&Asm[wm0 + mt * 16 + cl][km * 32 + kg * 8];
            #pragma unroll
            for (int nt = 0; nt < 2; ++nt)
                #pragma unroll
                for (int km = 0; km < 2; ++km)
                    bf[nt][km] = *(const short8*)&Bsm[wn0 + nt * 16 + cl][km * 32 + kg * 8];
            #pragma unroll
            for (int mt = 0; mt < 4; ++mt)
                #pragma unroll
                for (int nt = 0; nt < 2; ++nt)
                    #pragma unroll
                    for (int km = 0; km < 2; ++km)
                        acc[mt][nt] = __builtin_amdgcn_mfma_f32_16x16x32_bf16(af[mt][km], bf[nt][km], acc[mt][nt], 0, 0, 0);
        };

        __syncthreads();   // all waves done with phase-1 use of nothing shared; enter LDS cleanly
        gload(sA0, sB0, 0);
        for (int ks = 0; ks < 12; ks += 2) {
            swrite(sA0, sB0);
            __syncthreads();
            gload(sA1, sB1, (ks + 1) * 64);
            compute();
            __syncthreads();
            swrite(sA1, sB1);
            __syncthreads();
            if (ks + 2 < 12) gload(sA0, sB0, (ks + 2) * 64);
            compute();
            __syncthreads();
        }

        float bv[2];
        bv[0] = pb[c0 + wn0 + cl];
        bv[1] = pb[c0 + wn0 + 16 + cl];

        #pragma unroll
        for (int mt = 0; mt < 4; ++mt)
            #pragma unroll
            for (int nt = 0; nt < 2; ++nt)
                #pragma unroll
                for (int r = 0; r < 4; ++r)
                    out[(r0 + wm0 + mt * 16 + kg * 4 + r) * ND + c0 + wn0 + nt * 16 + cl]
                        = acc[mt][nt][r] + bv[nt];
    }
}

extern "C" void kernel_launch(void* const* d_in, const int* in_sizes, int n_in,
                              void* d_out, int out_size, void* d_ws, size_t ws_size,
                              hipStream_t stream) {
    const float* hs  = (const float*)d_in[0];
    const int*   wid = (const int*)d_in[1];
    const float* pw  = (const float*)d_in[2];
    const float* pb  = (const float*)d_in[3];
    float* out = (float*)d_out;

    unsigned short* wt = (unsigned short*)d_ws;                      // 393216 B
    int* bounds        = (int*)((char*)d_ws + 393216);               // 65792 B
    unsigned short* we = (unsigned short*)((char*)d_ws + 524288);    // 25165824 B

    void* args[] = { (void*)&hs, (void*)&wid, (void*)&pw, (void*)&pb,
                     (void*)&wt, (void*)&bounds, (void*)&we, (void*)&out };
    hipLaunchCooperativeKernel((const void*)mega, dim3(512), dim3(256),
                               args, 0, stream);
}

// Round 11
// 116.788 us; speedup vs baseline: 1.4892x; 1.4892x over previous
//
#include <hip/hip_runtime.h>

// BertWordEmbedder: B=64, T=512, H=768, W=256, D=256
// MEASUREMENT ROUND: R9 pipeline, pool body x3 and gemm body x5 (idempotent
// repeats, identical output) so both kernels exceed the 57us harness fills
// and surface in rocprof top-5 with full counters. True cost = dur/REP.
// ws: [0) wt 393216 | [393216) bounds 65792 | [524288) we 25165824

#define NB 64
#define NT 512
#define NH 768
#define NW 256
#define ND 256
#define REP_POOL 3
#define REP_GEMM 5

typedef __attribute__((ext_vector_type(8))) short short8;
typedef __attribute__((ext_vector_type(4))) float f32x4;
typedef __attribute__((ext_vector_type(4))) float float4v;
typedef __attribute__((ext_vector_type(4))) unsigned int uint4v;
typedef __attribute__((ext_vector_type(4))) unsigned short ushort4v;

__device__ __forceinline__ unsigned short f2bf(float f) {
    union { float f; unsigned u; } v; v.f = f;
    unsigned r = v.u + 0x7fffu + ((v.u >> 16) & 1u);  // RNE
    return (unsigned short)(r >> 16);
}

// merged prep: wt transpose (192 blocks) + bounds (64 blocks)
__global__ void prep(const float* __restrict__ w, const int* __restrict__ wid,
                     unsigned short* __restrict__ wt, int* __restrict__ bounds) {
    __shared__ float tile[32][33];
    __shared__ int s[NT];
    const int tid = threadIdx.x, n = blockIdx.x;
    if (n < 192) {
        int tx = tid & 31, ty = tid >> 5;
        int k0 = (n % 24) * 32, n0 = (n / 24) * 32;
        #pragma unroll
        for (int i = 0; i < 4; ++i)
            tile[ty + 8 * i][tx] = w[(size_t)(k0 + ty + 8 * i) * ND + n0 + tx];
        __syncthreads();
        #pragma unroll
        for (int i = 0; i < 4; ++i)
            wt[(size_t)(n0 + ty + 8 * i) * NH + k0 + tx] = f2bf(tile[tx][ty + 8 * i]);
    } else {
        int b = n - 192;
        s[tid]       = wid[b * NT + tid];
        s[tid + 256] = wid[b * NT + tid + 256];
        __syncthreads();
        for (int w2 = tid; w2 <= NW; w2 += 256) {
            int lo = 0, hi = NT;
            while (lo < hi) { int m = (lo + hi) >> 1; if (s[m] < w2) lo = m + 1; else hi = m; }
            bounds[b * (NW + 1) + w2] = lo;
        }
    }
}

// one wave per word PAIR; body repeated REP_POOL x (measurement)
__global__ __launch_bounds__(256, 8)
void pool_pair(const float* __restrict__ hs, const int* __restrict__ bounds,
               unsigned short* __restrict__ we) {
    const int wave = threadIdx.x >> 6, lane = threadIdx.x & 63;
    const int idx = blockIdx.x * 4 + wave;          // 0..8191 = (b, wordpair j)
    const int b = idx >> 7, j = idx & 127;

    for (int rep = 0; rep < REP_POOL; ++rep) {
        const int* bp = bounds + b * (NW + 1) + 2 * j;
        int s = __builtin_amdgcn_readfirstlane(bp[0]);
        int m = __builtin_amdgcn_readfirstlane(bp[1]);
        int e = __builtin_amdgcn_readfirstlane(bp[2]);

        const float* base = hs + (size_t)b * NT * NH + lane * 4;
        float4v a0c0 = {0,0,0,0}, a0c1 = {0,0,0,0}, a0c2 = {0,0,0,0};
        float4v a1c0 = {0,0,0,0}, a1c1 = {0,0,0,0}, a1c2 = {0,0,0,0};

#define ROUTE(t, v0, v1, v2) {                                                \
        if ((t) < m) {                                                        \
            _Pragma("unroll") for (int q = 0; q < 4; ++q) {                   \
                a0c0[q] += (v0)[q]; a0c1[q] += (v1)[q]; a0c2[q] += (v2)[q]; } \
        } else {                                                              \
            _Pragma("unroll") for (int q = 0; q < 4; ++q) {                   \
                a1c0[q] += (v0)[q]; a1c1[q] += (v1)[q]; a1c2[q] += (v2)[q]; } \
        }                                                                     \
    }
        int t = s;
        for (; t + 2 <= e; t += 2) {
            float4v v[2][3];
            #pragma unroll
            for (int u = 0; u < 2; ++u) {
                const float* p = base + (size_t)(t + u) * NH;
                v[u][0] = *(const float4v*)(p);
                v[u][1] = *(const float4v*)(p + 256);
                v[u][2] = *(const float4v*)(p + 512);
            }
            #pragma unroll
            for (int u = 0; u < 2; ++u) ROUTE(t + u, v[u][0], v[u][1], v[u][2]);
        }
        if (t < e) {
            const float* p = base + (size_t)t * NH;
            float4v v0 = *(const float4v*)(p);
            float4v v1 = *(const float4v*)(p + 256);
            float4v v2 = *(const float4v*)(p + 512);
            ROUTE(t, v0, v1, v2);
        }
#undef ROUTE
        int c0 = m - s; if (c0 < 1) c0 = 1;
        int c1 = e - m; if (c1 < 1) c1 = 1;
        const float s0 = 1.0f / (float)c0, s1 = 1.0f / (float)c1;

        unsigned short* d0 = we + (size_t)(2 * idx) * NH + lane * 4;
        unsigned short* d1 = d0 + NH;
        ushort4v u;
        #pragma unroll
        for (int q = 0; q < 4; ++q) u[q] = f2bf(a0c0[q] * s0);
        *(ushort4v*)(d0) = u;
        #pragma unroll
        for (int q = 0; q < 4; ++q) u[q] = f2bf(a0c1[q] * s0);
        *(ushort4v*)(d0 + 256) = u;
        #pragma unroll
        for (int q = 0; q < 4; ++q) u[q] = f2bf(a0c2[q] * s0);
        *(ushort4v*)(d0 + 512) = u;
        #pragma unroll
        for (int q = 0; q < 4; ++q) u[q] = f2bf(a1c0[q] * s1);
        *(ushort4v*)(d1) = u;
        #pragma unroll
        for (int q = 0; q < 4; ++q) u[q] = f2bf(a1c1[q] * s1);
        *(ushort4v*)(d1 + 256) = u;
        #pragma unroll
        for (int q = 0; q < 4; ++q) u[q] = f2bf(a1c2[q] * s1);
        *(ushort4v*)(d1 + 512) = u;
    }
}

// out = we @ wt^T + bias; body repeated REP_GEMM x (measurement)
__global__ __launch_bounds__(256)
void gemm_lds(const unsigned short* __restrict__ we, const unsigned short* __restrict__ wt,
              const float* __restrict__ bias, float* __restrict__ out) {
    __shared__ unsigned short Asm[128][72];
    __shared__ unsigned short Bsm[64][72];

    const int tid = threadIdx.x, wave = tid >> 6, lane = tid & 63;
    const int cl = lane & 15, kg = lane >> 4;
    const int bid = blockIdx.x;                     // 0..511
    const int swz = (bid & 7) * 64 + (bid >> 3);    // bijective (512 % 8 == 0)
    const size_t r0 = (size_t)(swz >> 2) * 128;
    const int c0 = (swz & 3) * 64;
    const int wm0 = (wave >> 1) * 64, wn0 = (wave & 1) * 32;

    const int arow = tid >> 1, ah = tid & 1;
    const int brow = tid >> 2, bq = tid & 3;
    const unsigned short* agp = we + (r0 + arow) * NH;
    const unsigned short* bgp = wt + (size_t)(c0 + brow) * NH;

    for (int rep = 0; rep < REP_GEMM; ++rep) {
        uint4v sA0[4], sB0[2], sA1[4], sB1[2];

        auto gload = [&](uint4v* sA, uint4v* sB, int k0e) {
            #pragma unroll
            for (int i = 0; i < 4; ++i)
                sA[i] = *(const uint4v*)(agp + k0e + (ah + 2 * i) * 8);
            #pragma unroll
            for (int i = 0; i < 2; ++i)
                sB[i] = *(const uint4v*)(bgp + k0e + (bq + 4 * i) * 8);
        };
        auto swrite = [&](uint4v* sA, uint4v* sB) {
            #pragma unroll
            for (int i = 0; i < 4; ++i)
                *(uint4v*)&Asm[arow][(ah + 2 * i) * 8] = sA[i];
            #pragma unroll
            for (int i = 0; i < 2; ++i)
                *(uint4v*)&Bsm[brow][(bq + 4 * i) * 8] = sB[i];
        };

        f32x4 acc[4][2];
        #pragma unroll
        for (int mt = 0; mt < 4; ++mt)
            #pragma unroll
            for (int nt = 0; nt < 2; ++nt)
                #pragma unroll
                for (int r = 0; r < 4; ++r) acc[mt][nt][r] = 0.f;

        auto compute = [&]() {
            short8 af[4][2], bf[2][2];
            #pragma unroll
            for (int mt = 0; mt < 4; ++mt)
                #pragma unroll
                for (int km = 0; km < 2; ++km)
                    af[mt][km] = *(const short8*)&Asm[wm0 + mt * 16 + cl][km * 32 + kg * 8];
            #pragma unroll
            for (int nt = 0; nt < 2; ++nt)
                #pragma unroll
                for (int km = 0; km < 2; ++km)
                    bf[nt][km] = *(const short8*)&Bsm[wn0 + nt * 16 + cl][km * 32 + kg * 8];
            #pragma unroll
            for (int mt = 0; mt < 4; ++mt)
                #pragma unroll
                for (int nt = 0; nt < 2; ++nt)
                    #pragma unroll
                    for (int km = 0; km < 2; ++km)
                        acc[mt][nt] = __builtin_amdgcn_mfma_f32_16x16x32_bf16(af[mt][km], bf[nt][km], acc[mt][nt], 0, 0, 0);
        };

        __syncthreads();                            // rep boundary: LDS reuse safe
        gload(sA0, sB0, 0);
        for (int ks = 0; ks < 12; ks += 2) {
            swrite(sA0, sB0);
            __syncthreads();
            gload(sA1, sB1, (ks + 1) * 64);
            compute();
            __syncthreads();
            swrite(sA1, sB1);
            __syncthreads();
            if (ks + 2 < 12) gload(sA0, sB0, (ks + 2) * 64);
            compute();
            __syncthreads();
        }

        float bv[2];
        bv[0] = bias[c0 + wn0 + cl];
        bv[1] = bias[c0 + wn0 + 16 + cl];

        #pragma unroll
        for (int mt = 0; mt < 4; ++mt)
            #pragma unroll
            for (int nt = 0; nt < 2; ++nt)
                #pragma unroll
                for (int r = 0; r < 4; ++r)
                    out[(r0 + wm0 + mt * 16 + kg * 4 + r) * ND + c0 + wn0 + nt * 16 + cl]
                        = acc[mt][nt][r] + bv[nt];
    }
}

extern "C" void kernel_launch(void* const* d_in, const int* in_sizes, int n_in,
                              void* d_out, int out_size, void* d_ws, size_t ws_size,
                              hipStream_t stream) {
    const float* hs  = (const float*)d_in[0];
    const int*   wid = (const int*)d_in[1];
    const float* pw  = (const float*)d_in[2];
    const float* pb  = (const float*)d_in[3];
    float* out = (float*)d_out;

    unsigned short* wt = (unsigned short*)d_ws;                      // 393216 B
    int* bounds        = (int*)((char*)d_ws + 393216);               // 65792 B
    unsigned short* we = (unsigned short*)((char*)d_ws + 524288);    // 25165824 B

    prep<<<256, 256, 0, stream>>>(pw, wid, wt, bounds);
    pool_pair<<<(NB * NW / 2) / 4, 256, 0, stream>>>(hs, bounds, we);
    gemm_lds<<<NB * NW / 128 * (ND / 64), 256, 0, stream>>>(we, wt, pb, out);
}

// Round 12
// 44.777 us; speedup vs baseline: 3.8841x; 2.6082x over previous
//
#include <hip/hip_runtime.h>

// BertWordEmbedder: B=64, T=512, H=768, W=256, D=256
//   prep:      [0..191] proj_w -> wt [256][768] bf16 ; [192..255] bounds
//   pool_pair: one WAVE per word pair (R8-proven, CONTROL)  -> we bf16
//   gemm_lds:  R12: BM=64 BN=64 BK=64 -> 1024 blocks (4/CU), double-buffered
//              LDS w/ 1 barrier per K-step, XOR chunk-swizzle (stride 64),
//              XCD-chunked block swizzle, launch_bounds(256,4).
// ws: [0) wt 393216 | [393216) bounds 65792 | [524288) we 25165824

#define NB 64
#define NT 512
#define NH 768
#define NW 256
#define ND 256

typedef __attribute__((ext_vector_type(8))) short short8;
typedef __attribute__((ext_vector_type(4))) float f32x4;
typedef __attribute__((ext_vector_type(4))) float float4v;
typedef __attribute__((ext_vector_type(4))) unsigned int uint4v;
typedef __attribute__((ext_vector_type(4))) unsigned short ushort4v;

__device__ __forceinline__ unsigned short f2bf(float f) {
    union { float f; unsigned u; } v; v.f = f;
    unsigned r = v.u + 0x7fffu + ((v.u >> 16) & 1u);  // RNE
    return (unsigned short)(r >> 16);
}

// merged prep: wt transpose (192 blocks) + bounds (64 blocks)
__global__ void prep(const float* __restrict__ w, const int* __restrict__ wid,
                     unsigned short* __restrict__ wt, int* __restrict__ bounds) {
    __shared__ float tile[32][33];
    __shared__ int s[NT];
    const int tid = threadIdx.x, n = blockIdx.x;
    if (n < 192) {
        int tx = tid & 31, ty = tid >> 5;
        int k0 = (n % 24) * 32, n0 = (n / 24) * 32;
        #pragma unroll
        for (int i = 0; i < 4; ++i)
            tile[ty + 8 * i][tx] = w[(size_t)(k0 + ty + 8 * i) * ND + n0 + tx];
        __syncthreads();
        #pragma unroll
        for (int i = 0; i < 4; ++i)
            wt[(size_t)(n0 + ty + 8 * i) * NH + k0 + tx] = f2bf(tile[tx][ty + 8 * i]);
    } else {
        int b = n - 192;
        s[tid]       = wid[b * NT + tid];
        s[tid + 256] = wid[b * NT + tid + 256];
        __syncthreads();
        for (int w2 = tid; w2 <= NW; w2 += 256) {
            int lo = 0, hi = NT;
            while (lo < hi) { int m = (lo + hi) >> 1; if (s[m] < w2) lo = m + 1; else hi = m; }
            bounds[b * (NW + 1) + w2] = lo;
        }
    }
}

// one wave per word PAIR (CONTROL: unchanged from R8/R9)
__global__ __launch_bounds__(256, 8)
void pool_pair(const float* __restrict__ hs, const int* __restrict__ bounds,
               unsigned short* __restrict__ we) {
    const int wave = threadIdx.x >> 6, lane = threadIdx.x & 63;
    const int idx = blockIdx.x * 4 + wave;          // 0..8191 = (b, wordpair j)
    const int b = idx >> 7, j = idx & 127;

    const int* bp = bounds + b * (NW + 1) + 2 * j;
    int s = __builtin_amdgcn_readfirstlane(bp[0]);
    int m = __builtin_amdgcn_readfirstlane(bp[1]);
    int e = __builtin_amdgcn_readfirstlane(bp[2]);

    const float* base = hs + (size_t)b * NT * NH + lane * 4;
    float4v a0c0 = {0,0,0,0}, a0c1 = {0,0,0,0}, a0c2 = {0,0,0,0};
    float4v a1c0 = {0,0,0,0}, a1c1 = {0,0,0,0}, a1c2 = {0,0,0,0};

#define ROUTE(t, v0, v1, v2) {                                                \
        if ((t) < m) {                                                        \
            _Pragma("unroll") for (int q = 0; q < 4; ++q) {                   \
                a0c0[q] += (v0)[q]; a0c1[q] += (v1)[q]; a0c2[q] += (v2)[q]; } \
        } else {                                                              \
            _Pragma("unroll") for (int q = 0; q < 4; ++q) {                   \
                a1c0[q] += (v0)[q]; a1c1[q] += (v1)[q]; a1c2[q] += (v2)[q]; } \
        }                                                                     \
    }
    int t = s;
    for (; t + 2 <= e; t += 2) {
        float4v v[2][3];
        #pragma unroll
        for (int u = 0; u < 2; ++u) {
            const float* p = base + (size_t)(t + u) * NH;
            v[u][0] = *(const float4v*)(p);
            v[u][1] = *(const float4v*)(p + 256);
            v[u][2] = *(const float4v*)(p + 512);
        }
        #pragma unroll
        for (int u = 0; u < 2; ++u) ROUTE(t + u, v[u][0], v[u][1], v[u][2]);
    }
    if (t < e) {
        const float* p = base + (size_t)t * NH;
        float4v v0 = *(const float4v*)(p);
        float4v v1 = *(const float4v*)(p + 256);
        float4v v2 = *(const float4v*)(p + 512);
        ROUTE(t, v0, v1, v2);
    }
#undef ROUTE

    int c0 = m - s; if (c0 < 1) c0 = 1;
    int c1 = e - m; if (c1 < 1) c1 = 1;
    const float s0 = 1.0f / (float)c0, s1 = 1.0f / (float)c1;

    unsigned short* d0 = we + (size_t)(2 * idx) * NH + lane * 4;
    unsigned short* d1 = d0 + NH;
    ushort4v u;
    #pragma unroll
    for (int q = 0; q < 4; ++q) u[q] = f2bf(a0c0[q] * s0);
    *(ushort4v*)(d0) = u;
    #pragma unroll
    for (int q = 0; q < 4; ++q) u[q] = f2bf(a0c1[q] * s0);
    *(ushort4v*)(d0 + 256) = u;
    #pragma unroll
    for (int q = 0; q < 4; ++q) u[q] = f2bf(a0c2[q] * s0);
    *(ushort4v*)(d0 + 512) = u;
    #pragma unroll
    for (int q = 0; q < 4; ++q) u[q] = f2bf(a1c0[q] * s1);
    *(ushort4v*)(d1) = u;
    #pragma unroll
    for (int q = 0; q < 4; ++q) u[q] = f2bf(a1c1[q] * s1);
    *(ushort4v*)(d1 + 256) = u;
    #pragma unroll
    for (int q = 0; q < 4; ++q) u[q] = f2bf(a1c2[q] * s1);
    *(ushort4v*)(d1 + 512) = u;
}

// out[16384x256] = we @ wt^T + bias.
// BM=64 BN=64 BK=64, 1024 blocks (4/CU), 4 waves (2x2, each 32x32 out).
// Double-buffered LDS, ONE barrier per K-step; loads issued one step early.
// LDS stride 64 (natural), XOR chunk-swizzle: chunk ^= (row & 7).
__global__ __launch_bounds__(256, 4)
void gemm_lds(const unsigned short* __restrict__ we, const unsigned short* __restrict__ wt,
              const float* __restrict__ bias, float* __restrict__ out) {
    __shared__ unsigned short Abuf[2][64][64];
    __shared__ unsigned short Bbuf[2][64][64];

    const int tid = threadIdx.x, wave = tid >> 6, lane = tid & 63;
    const int cl = lane & 15, kg = lane >> 4;
    const int bid = blockIdx.x;                       // 0..1023
    const int swz = (bid & 7) * 128 + (bid >> 3);     // bijective (1024 % 8 == 0)
    const size_t r0 = (size_t)(swz >> 2) * 64;
    const int c0 = (swz & 3) * 64;
    const int wm0 = (wave >> 1) * 32, wn0 = (wave & 1) * 32;

    // staging: row = tid>>2 (0..63), two 16B chunks: sc and sc+4
    const int srow = tid >> 2, sc = tid & 3;
    const int p0 = (sc ^ (srow & 7)) * 8;             // swizzled ushort offsets
    const int p1 = ((sc + 4) ^ (srow & 7)) * 8;
    const unsigned short* agp = we + (r0 + srow) * NH + sc * 8;
    const unsigned short* bgp = wt + (size_t)(c0 + srow) * NH + sc * 8;

    uint4v ra0[2], rb0[2], ra1[2], rb1[2];

#define GLOAD(ra, rb, ks) {                                                   \
        ra[0] = *(const uint4v*)(agp + (ks) * 64);                            \
        ra[1] = *(const uint4v*)(agp + (ks) * 64 + 32);                       \
        rb[0] = *(const uint4v*)(bgp + (ks) * 64);                            \
        rb[1] = *(const uint4v*)(bgp + (ks) * 64 + 32);                       \
    }
#define SWRITE(buf, ra, rb) {                                                 \
        *(uint4v*)&Abuf[buf][srow][p0] = ra[0];                               \
        *(uint4v*)&Abuf[buf][srow][p1] = ra[1];                               \
        *(uint4v*)&Bbuf[buf][srow][p0] = rb[0];                               \
        *(uint4v*)&Bbuf[buf][srow][p1] = rb[1];                               \
    }

    f32x4 acc[2][2];
    #pragma unroll
    for (int mt = 0; mt < 2; ++mt)
        #pragma unroll
        for (int nt = 0; nt < 2; ++nt)
            #pragma unroll
            for (int r = 0; r < 4; ++r) acc[mt][nt][r] = 0.f;

    auto compute = [&](int buf) {
        short8 af[2][2], bf[2][2];
        #pragma unroll
        for (int mt = 0; mt < 2; ++mt)
            #pragma unroll
            for (int km = 0; km < 2; ++km) {
                int row = wm0 + mt * 16 + cl;
                af[mt][km] = *(const short8*)&Abuf[buf][row][((km * 4 + kg) ^ (row & 7)) * 8];
            }
        #pragma unroll
        for (int nt = 0; nt < 2; ++nt)
            #pragma unroll
            for (int km = 0; km < 2; ++km) {
                int row = wn0 + nt * 16 + cl;
                bf[nt][km] = *(const short8*)&Bbuf[buf][row][((km * 4 + kg) ^ (row & 7)) * 8];
            }
        #pragma unroll
        for (int mt = 0; mt < 2; ++mt)
            #pragma unroll
            for (int nt = 0; nt < 2; ++nt)
                #pragma unroll
                for (int km = 0; km < 2; ++km)
                    acc[mt][nt] = __builtin_amdgcn_mfma_f32_16x16x32_bf16(af[mt][km], bf[nt][km], acc[mt][nt], 0, 0, 0);
    };

    // prologue: tile0 -> buf0, tile1 staged in regs
    GLOAD(ra0, rb0, 0);
    SWRITE(0, ra0, rb0);
    GLOAD(ra1, rb1, 1);
    __syncthreads();

    #pragma unroll 1
    for (int ks = 0; ks < 12; ks += 2) {
        // step ks: compute buf0 (tile ks); write tile ks+1 -> buf1; load ks+2
        if (ks + 2 < 12) GLOAD(ra0, rb0, ks + 2);
        SWRITE(1, ra1, rb1);
        compute(0);
        __syncthreads();
        // step ks+1: compute buf1 (tile ks+1); write ks+2 -> buf0; load ks+3
        if (ks + 3 < 12) GLOAD(ra1, rb1, ks + 3);
        if (ks + 2 < 12) SWRITE(0, ra0, rb0);
        compute(1);
        __syncthreads();
    }
#undef GLOAD
#undef SWRITE

    float bv[2];
    bv[0] = bias[c0 + wn0 + cl];
    bv[1] = bias[c0 + wn0 + 16 + cl];

    // C/D layout: col=lane&15, row=(lane>>4)*4+r  [proven R1-R11]
    #pragma unroll
    for (int mt = 0; mt < 2; ++mt)
        #pragma unroll
        for (int nt = 0; nt < 2; ++nt)
            #pragma unroll
            for (int r = 0; r < 4; ++r)
                out[(r0 + wm0 + mt * 16 + kg * 4 + r) * ND + c0 + wn0 + nt * 16 + cl]
                    = acc[mt][nt][r] + bv[nt];
}

extern "C" void kernel_launch(void* const* d_in, const int* in_sizes, int n_in,
                              void* d_out, int out_size, void* d_ws, size_t ws_size,
                              hipStream_t stream) {
    const float* hs  = (const float*)d_in[0];
    const int*   wid = (const int*)d_in[1];
    const float* pw  = (const float*)d_in[2];
    const float* pb  = (const float*)d_in[3];
    float* out = (float*)d_out;

    unsigned short* wt = (unsigned short*)d_ws;                      // 393216 B
    int* bounds        = (int*)((char*)d_ws + 393216);               // 65792 B
    unsigned short* we = (unsigned short*)((char*)d_ws + 524288);    // 25165824 B

    prep<<<256, 256, 0, stream>>>(pw, wid, wt, bounds);
    pool_pair<<<(NB * NW / 2) / 4, 256, 0, stream>>>(hs, bounds, we);
    gemm_lds<<<NB * NW / 64 * (ND / 64), 256, 0, stream>>>(we, wt, pb, out);
}